// Round 16
// baseline (59.711 us; speedup 1.0000x reference)
//
#include <hip/hip_runtime.h>

// VectorQuantizer forward, fused 3-launch + coop cvt + LDS x-cache:
//   prep: codebook -> ws (eT f32, en2, en2b, bf16 hi+lo A-frags)  [2 blocks]
//   main (64 rows/block, 1024 blocks):
//     Phase0 cooperative x load -> padded f32 LDS cache + bf16 hi/lo frags
//     Phase1 3-term bf16 MFMA scan, TREE (min,2nd-min) pack reduction
//     Phase2 combine + near-tie flag
//     Phase3 exact rescan of flagged rows from LDS x (round-2 chain)
//     Phase4 epilogue out = x + (q-x) from LDS x; per-block loss slot (no atomic)
//   fin:  deterministic 1024-slot loss reduce + scalar write
//
// Metric: argmin_k ||f-e_k||^2 == argmin_k (en2[k]-2 f.e_k). Approx dot =
// fh.eh + fh.el + fl.eh (bf16 splits), residual fl.el sigma ~4e-6;
// TAU=1.2e-3 (validated rounds 5/12-15, absmax 0). en2b = en2+6 keeps the
// metric positive -> u32 bit-monotone pack, code idx in low 9 bits ==
// np.argmin first-index tie-break. Tree (min,2nd-min) computes exactly the
// same {m1,m2} as the previous chain (order-independent over distinct u32s).

#define N_ROWS 65536
#define DIM 64
#define KCODES 512
#define ROWS_PER_BLOCK 64
#define THREADS 512
#define XPAD 68   // xs row stride in floats (17x16B -> float4-aligned, 2-way banks)

typedef short s16x8 __attribute__((ext_vector_type(8)));
typedef float f32x4 __attribute__((ext_vector_type(4)));

// ws byte offsets
#define LSLOT_OFF  0         // 1024 x f64 per-block loss slots: 8 KB
#define EN2_OFF    8192
#define EN2B_OFF   10240
#define ET_OFF     12288     // f32 codebook rows: 128 KB
#define AFR_OFF    143360    // bf16 hi+lo A-frags: 128 KB

#define TAU 1.2e-3f

__device__ __forceinline__ unsigned short f2bf(float f) {
    unsigned u = __float_as_uint(f);
    return (unsigned short)((u + 0x7fffu + ((u >> 16) & 1u)) >> 16);
}
__device__ __forceinline__ float bf2f(unsigned short h) {
    return __uint_as_float(((unsigned)h) << 16);
}
// identical arithmetic to rounds 13-15 cvt8, inputs already loaded
__device__ __forceinline__ void cvt8v(const float4 v0, const float4 v1,
                                      s16x8& hi, s16x8& lo) {
    const float vv[8] = {v0.x, v0.y, v0.z, v0.w, v1.x, v1.y, v1.z, v1.w};
    #pragma unroll
    for (int j = 0; j < 8; ++j) {
        const unsigned short h = f2bf(vv[j]);
        hi[j] = (short)h;
        lo[j] = (short)f2bf(vv[j] - bf2f(h));
    }
}

// ---------------- prep: codebook only (2 blocks x 256 threads)
__global__ void vq_prep(const float* __restrict__ emb, char* __restrict__ ws) {
    const int k = blockIdx.x * 256 + threadIdx.x;   // code 0..511
    float* en2  = (float*)(ws + EN2_OFF);
    float* en2b = (float*)(ws + EN2B_OFF);
    float* eT   = (float*)(ws + ET_OFF);
    uint4* Afr  = (uint4*)(ws + AFR_OFF);
    const int ctg = k >> 4, c = k & 15;
    float s = 0.0f;
    #pragma unroll
    for (int ks = 0; ks < 2; ++ks) {
        #pragma unroll
        for (int g = 0; g < 4; ++g) {
            unsigned short hb[8], lb[8];
            #pragma unroll
            for (int j = 0; j < 8; ++j) {
                const int d = ks * 32 + g * 8 + j;
                const float v = emb[d * KCODES + k];   // coalesced across k
                eT[k * DIM + d] = v;
                s = fmaf(v, v, s);                     // same chain as round-2
                const unsigned short h = f2bf(v);
                hb[j] = h;
                lb[j] = f2bf(v - bf2f(h));
            }
            uint4 H, L;
            H.x = hb[0] | ((unsigned)hb[1] << 16); H.y = hb[2] | ((unsigned)hb[3] << 16);
            H.z = hb[4] | ((unsigned)hb[5] << 16); H.w = hb[6] | ((unsigned)hb[7] << 16);
            L.x = lb[0] | ((unsigned)lb[1] << 16); L.y = lb[2] | ((unsigned)lb[3] << 16);
            L.z = lb[4] | ((unsigned)lb[5] << 16); L.w = lb[6] | ((unsigned)lb[7] << 16);
            const int lane = g * 16 + c;
            Afr[((ctg * 2 + ks) * 2 + 0) * 64 + lane] = H;   // hi
            Afr[((ctg * 2 + ks) * 2 + 1) * 64 + lane] = L;   // lo
        }
    }
    en2[k] = s;
    en2b[k] = s + 6.0f;
}

// ---------------- main: coop cvt + scan + rescan + epilogue (64 rows/block)
__global__ __launch_bounds__(THREADS, 2)
void vq_main(const float* __restrict__ x, char* __restrict__ ws,
             float* __restrict__ out) {
    __shared__ float xs[ROWS_PER_BLOCK][XPAD];        // ~17 KB f32 x cache
    __shared__ s16x8 Bfr[4][2][2][64];                // 16 KB B-fragments
    __shared__ unsigned long long sm_all[4][8][16];   // 4 KB
    __shared__ unsigned pick[ROWS_PER_BLOCK];
    __shared__ unsigned char llist[ROWS_PER_BLOCK];
    __shared__ unsigned long long wmin[8];
    __shared__ double lpart[8];
    __shared__ int lcnt;

    const int tid = threadIdx.x;
    const int bid = blockIdx.x;
    const int w = __builtin_amdgcn_readfirstlane(tid >> 6);  // wave = 64-code group
    const int l = tid & 63;
    if (tid == 0) lcnt = 0;

    // Phase 0: cooperative x load -> LDS f32 cache + frag conversion.
    {
        const int r_abs = tid >> 3;          // 0..63
        const int jg    = tid & 7;           // 8-dim group 0..7
        const float* p = x + (size_t)(bid * ROWS_PER_BLOCK + r_abs) * DIM + jg * 8;
        const float4 v0 = *(const float4*)p;
        const float4 v1 = *(const float4*)(p + 4);
        *(float4*)&xs[r_abs][jg * 8]     = v0;
        *(float4*)&xs[r_abs][jg * 8 + 4] = v1;
        s16x8 h, lo;
        cvt8v(v0, v1, h, lo);
        const int rt = r_abs >> 4, c = r_abs & 15;
        Bfr[rt][jg >> 2][0][(jg & 3) * 16 + c] = h;
        Bfr[rt][jg >> 2][1][(jg & 3) * 16 + c] = lo;
    }

    // A-fragments: this wave's 64 codes (4 ctiles x 2 ksteps), bf16 hi+lo.
    const s16x8* Afr = (const s16x8*)(ws + AFR_OFF);
    s16x8 Aeh[4][2], Ael[4][2];
    #pragma unroll
    for (int ct = 0; ct < 4; ++ct) {
        #pragma unroll
        for (int ks = 0; ks < 2; ++ks) {
            const int ctg = w * 4 + ct;
            Aeh[ct][ks] = Afr[((ctg * 2 + ks) * 2 + 0) * 64 + l];
            Ael[ct][ks] = Afr[((ctg * 2 + ks) * 2 + 1) * 64 + l];
        }
    }
    const float* en2b = (const float*)(ws + EN2B_OFF);
    f32x4 enf[4];
    #pragma unroll
    for (int ct = 0; ct < 4; ++ct) {
        const float4 t = *(const float4*)(en2b + w * 64 + ct * 16 + (l >> 4) * 4);
        enf[ct][0] = t.x; enf[ct][1] = t.y; enf[ct][2] = t.z; enf[ct][3] = t.w;
    }
    const int codebase = w * 64 + (l >> 4) * 4;

    __syncthreads();   // B-frags + xs ready

    // Phase 1: scan 4 row-tiles; tree (min,2nd-min) over 16 packed candidates.
    #pragma unroll 2
    for (int bt = 0; bt < 4; ++bt) {
        const s16x8 bh0 = Bfr[bt][0][0][l];
        const s16x8 bl0 = Bfr[bt][0][1][l];
        const s16x8 bh1 = Bfr[bt][1][0][l];
        const s16x8 bl1 = Bfr[bt][1][1][l];

        unsigned uu[16];
        #pragma unroll
        for (int ct = 0; ct < 4; ++ct) {
            f32x4 a = {0.f, 0.f, 0.f, 0.f};
            a = __builtin_amdgcn_mfma_f32_16x16x32_bf16(Aeh[ct][0], bh0, a, 0, 0, 0);
            a = __builtin_amdgcn_mfma_f32_16x16x32_bf16(Aeh[ct][1], bh1, a, 0, 0, 0);
            a = __builtin_amdgcn_mfma_f32_16x16x32_bf16(Ael[ct][0], bh0, a, 0, 0, 0);
            a = __builtin_amdgcn_mfma_f32_16x16x32_bf16(Ael[ct][1], bh1, a, 0, 0, 0);
            a = __builtin_amdgcn_mfma_f32_16x16x32_bf16(Aeh[ct][0], bl0, a, 0, 0, 0);
            a = __builtin_amdgcn_mfma_f32_16x16x32_bf16(Aeh[ct][1], bl1, a, 0, 0, 0);
            #pragma unroll
            for (int rg = 0; rg < 4; ++rg) {
                const float m = fmaf(-2.0f, a[rg], enf[ct][rg]);
                uu[ct * 4 + rg] = (__float_as_uint(m) & 0xFFFFFE00u)
                                | (unsigned)(codebase + ct * 16 + rg);
            }
        }
        // balanced (min, 2nd-min) tree: same results as the former chain.
        unsigned b1[8], b2[8];
        #pragma unroll
        for (int i = 0; i < 8; ++i) {
            const unsigned u = uu[2 * i], v = uu[2 * i + 1];
            b1[i] = u < v ? u : v;
            b2[i] = u < v ? v : u;
        }
        #pragma unroll
        for (int st = 4; st > 0; st >>= 1) {
            #pragma unroll
            for (int i = 0; i < st; ++i) {
                const unsigned x1 = b1[i], y1 = b1[i + st];
                const unsigned lo = x1 < y1 ? x1 : y1;
                const unsigned hi = x1 < y1 ? y1 : x1;
                const unsigned s2 = b2[i] < b2[i + st] ? b2[i] : b2[i + st];
                b1[i] = lo;
                b2[i] = s2 < hi ? s2 : hi;
            }
        }
        unsigned m1 = b1[0], m2 = b2[0];
        #pragma unroll
        for (int mask = 16; mask <= 32; mask <<= 1) {
            const unsigned o1 = __shfl_xor(m1, mask);
            const unsigned o2 = __shfl_xor(m2, mask);
            const unsigned hi  = m1 > o1 ? m1 : o1;
            const unsigned lo2 = m2 < o2 ? m2 : o2;
            m1 = m1 < o1 ? m1 : o1;
            m2 = hi < lo2 ? hi : lo2;
        }
        if (l < 16) sm_all[bt][w][l] = ((unsigned long long)m1 << 32) | m2;
    }
    __syncthreads();

    // Phase 2: combine 8 waves per row; flag near-ties (block-local list).
    if (tid < ROWS_PER_BLOCK) {
        const int bt = tid >> 4, c = tid & 15;
        unsigned long long p = sm_all[bt][0][c];
        unsigned m1 = (unsigned)(p >> 32), m2 = (unsigned)p;
        #pragma unroll
        for (int w2 = 1; w2 < 8; ++w2) {
            p = sm_all[bt][w2][c];
            const unsigned a1 = (unsigned)(p >> 32), a2 = (unsigned)p;
            const unsigned hi  = m1 > a1 ? m1 : a1;
            const unsigned lo2 = m2 < a2 ? m2 : a2;
            m1 = m1 < a1 ? m1 : a1;
            m2 = hi < lo2 ? hi : lo2;
        }
        pick[tid] = m1 & 0x1FFu;
        const float f1 = __uint_as_float(m1 & 0xFFFFFE00u);
        const float f2 = __uint_as_float(m2 & 0xFFFFFE00u);
        if (f2 - f1 < TAU) {
            const int i = atomicAdd(&lcnt, 1);
            llist[i] = (unsigned char)tid;
        }
    }
    __syncthreads();

    // Phase 3: exact f32 rescan of flagged rows (1 code/thread, row from LDS;
    // round-2-identical per-code chain; u64 min == np.argmin tie-break).
    {
        const float* eT  = (const float*)(ws + ET_OFF);
        const float* en2 = (const float*)(ws + EN2_OFF);
        const int nfb = lcnt;
        for (int i = 0; i < nfb; ++i) {
            const int r = llist[i];
            const float4* fr = (const float4*)xs[r];   // broadcast LDS reads

            float4 a4 = make_float4(0.f, 0.f, 0.f, 0.f);
            #pragma unroll
            for (int j = 0; j < 16; ++j) {
                const float4 f = fr[j];
                a4.x = fmaf(f.x, f.x, a4.x);
                a4.y = fmaf(f.y, f.y, a4.y);
                a4.z = fmaf(f.z, f.z, a4.z);
                a4.w = fmaf(f.w, f.w, a4.w);
            }
            const float r2 = (a4.x + a4.y) + (a4.z + a4.w);

            const int k = tid;   // one code per thread
            const float4* ek = (const float4*)(eT + k * DIM);
            float4 acc4 = make_float4(0.f, 0.f, 0.f, 0.f);
            #pragma unroll
            for (int j = 0; j < 16; ++j) {
                const float4 e = ek[j];
                const float4 f = fr[j];
                acc4.x = fmaf(f.x, e.x, acc4.x);
                acc4.y = fmaf(f.y, e.y, acc4.y);
                acc4.z = fmaf(f.z, e.z, acc4.z);
                acc4.w = fmaf(f.w, e.w, acc4.w);
            }
            const float dot = (acc4.x + acc4.y) + (acc4.z + acc4.w);
            const float s = (r2 + en2[k]) - 2.0f * dot;
            unsigned long long best =
                ((unsigned long long)__float_as_uint(s) << 32) | (unsigned)k;
            #pragma unroll
            for (int mask = 1; mask <= 32; mask <<= 1) {
                const unsigned long long o = __shfl_xor(best, mask);
                if (o < best) best = o;
            }
            if (l == 0) wmin[w] = best;
            __syncthreads();
            if (tid == 0) {
                unsigned long long b = wmin[0];
                #pragma unroll
                for (int t = 1; t < 8; ++t) if (wmin[t] < b) b = wmin[t];
                pick[r] = (unsigned)(b & 0x1FFu);
            }
            __syncthreads();
        }
    }
    __syncthreads();

    // Phase 4: out = x + (q - x) and loss; x from LDS, 8 threads/row.
    {
        const float* eT = (const float*)(ws + ET_OFF);
        const int r = tid >> 3, g8 = tid & 7;
        const int grow = bid * ROWS_PER_BLOCK + r;
        const float4* xr = (const float4*)&xs[r][g8 * 8];
        const float4* qr = (const float4*)(eT + pick[r] * DIM) + g8 * 2;
        float4* orow = ((float4*)out) + (size_t)grow * 16 + g8 * 2;
        float lsum = 0.0f;
        #pragma unroll
        for (int j = 0; j < 2; ++j) {
            const float4 q = qr[j], xv = xr[j];
            float4 o; float dx;
            dx = q.x - xv.x; o.x = xv.x + dx; lsum = fmaf(dx, dx, lsum);
            dx = q.y - xv.y; o.y = xv.y + dx; lsum = fmaf(dx, dx, lsum);
            dx = q.z - xv.z; o.z = xv.z + dx; lsum = fmaf(dx, dx, lsum);
            dx = q.w - xv.w; o.w = xv.w + dx; lsum = fmaf(dx, dx, lsum);
            orow[j] = o;
        }
        double dl = (double)lsum;
        #pragma unroll
        for (int off = 32; off > 0; off >>= 1) dl += __shfl_down(dl, off);
        if (l == 0) lpart[w] = dl;
    }
    __syncthreads();
    if (tid == 0) {
        double s = lpart[0];
        #pragma unroll
        for (int t = 1; t < 8; ++t) s += lpart[t];
        ((double*)(ws + LSLOT_OFF))[bid] = s;   // plain store, no atomic
    }
}

// ---------------- fin: deterministic loss reduce over 1024 slots
__global__ __launch_bounds__(512)
void vq_fin(const double* __restrict__ slots, float* __restrict__ out) {
    __shared__ double sp[8];
    const int tid = threadIdx.x;
    double s = slots[tid] + slots[tid + 512];
    #pragma unroll
    for (int off = 32; off > 0; off >>= 1) s += __shfl_down(s, off);
    if ((tid & 63) == 0) sp[tid >> 6] = s;
    __syncthreads();
    if (tid == 0) {
        double t = sp[0];
        #pragma unroll
        for (int i = 1; i < 8; ++i) t += sp[i];
        out[N_ROWS * DIM] = (float)(1.25 * t * (1.0 / (double)(N_ROWS * DIM)));
    }
}

extern "C" void kernel_launch(void* const* d_in, const int* in_sizes, int n_in,
                              void* d_out, int out_size, void* d_ws, size_t ws_size,
                              hipStream_t stream) {
    const float* x   = (const float*)d_in[0];
    const float* emb = (const float*)d_in[1];
    float* out = (float*)d_out;
    char*  ws  = (char*)d_ws;

    vq_prep<<<2, 256, 0, stream>>>(emb, ws);
    vq_main<<<N_ROWS / ROWS_PER_BLOCK, THREADS, 0, stream>>>(x, ws, out);
    vq_fin<<<1, 512, 0, stream>>>((const double*)(ws + LSLOT_OFF), out);
}

// Round 17
// 58.956 us; speedup vs baseline: 1.0128x; 1.0128x over previous
//
#include <hip/hip_runtime.h>

// VectorQuantizer forward — round-14 structure + split MFMA chains + loss slots:
//   prep: codebook -> ws (eT f32, en2, en2b, bf16 hi+lo A-frags)  [2 blocks]
//   main (128 rows/block, 512 blocks):
//     Phase0 cooperative x->bf16 cvt into LDS frag layout (once/block)
//     Phase1 3-term bf16 MFMA scan, TWO independent 3-chains per ct (ILP)
//     Phase2 combine + near-tie flag
//     Phase3 exact rescan of flagged rows (round-2-identical chain)
//     Phase4 epilogue out = x + (q-x); per-block f64 loss slot (no atomics)
//   fin:  deterministic 512-slot loss reduce + scalar write
//
// Metric: argmin_k ||f-e_k||^2 == argmin_k (en2[k]-2 f.e_k). Approx dot =
// fh.eh + fh.el + fl.eh (bf16 splits); dropped-term error sigma ~6e-6,
// max ~4e-5; chain-split reorders f32 accumulation (~1e-7). TAU=1.2e-3 >>
// 2*eps_max -> rows with approx top-2 gap >= TAU provably match np.argmin;
// near-ties get the bit-exact round-2 rescan. en2b = en2+6 keeps the metric
// positive -> u32 bit-monotone pack, code idx in low 9 bits = first-index
// tie-break. cvt grouping identical to rounds 13/14.

#define N_ROWS 65536
#define DIM 64
#define KCODES 512
#define ROWS_PER_BLOCK 128
#define THREADS 512

typedef short s16x8 __attribute__((ext_vector_type(8)));
typedef float f32x4 __attribute__((ext_vector_type(4)));

// ws byte offsets
#define LSLOT_OFF  0         // 512 x f64 per-block loss slots: 4 KB
#define EN2_OFF    8192
#define EN2B_OFF   10240
#define ET_OFF     12288     // f32 codebook rows: 128 KB
#define AFR_OFF    143360    // bf16 hi+lo A-frags: 128 KB

#define TAU 1.2e-3f

__device__ __forceinline__ unsigned short f2bf(float f) {
    unsigned u = __float_as_uint(f);
    return (unsigned short)((u + 0x7fffu + ((u >> 16) & 1u)) >> 16);
}
__device__ __forceinline__ float bf2f(unsigned short h) {
    return __uint_as_float(((unsigned)h) << 16);
}
__device__ __forceinline__ void cvt8(const float* __restrict__ p,
                                     s16x8& hi, s16x8& lo) {
    const float4 v0 = *(const float4*)p;
    const float4 v1 = *(const float4*)(p + 4);
    const float vv[8] = {v0.x, v0.y, v0.z, v0.w, v1.x, v1.y, v1.z, v1.w};
    #pragma unroll
    for (int j = 0; j < 8; ++j) {
        const unsigned short h = f2bf(vv[j]);
        hi[j] = (short)h;
        lo[j] = (short)f2bf(vv[j] - bf2f(h));
    }
}

// ---------------- prep: codebook only (2 blocks x 256 threads)
__global__ void vq_prep(const float* __restrict__ emb, char* __restrict__ ws) {
    const int k = blockIdx.x * 256 + threadIdx.x;   // code 0..511
    float* en2  = (float*)(ws + EN2_OFF);
    float* en2b = (float*)(ws + EN2B_OFF);
    float* eT   = (float*)(ws + ET_OFF);
    uint4* Afr  = (uint4*)(ws + AFR_OFF);
    const int ctg = k >> 4, c = k & 15;
    float s = 0.0f;
    #pragma unroll
    for (int ks = 0; ks < 2; ++ks) {
        #pragma unroll
        for (int g = 0; g < 4; ++g) {
            unsigned short hb[8], lb[8];
            #pragma unroll
            for (int j = 0; j < 8; ++j) {
                const int d = ks * 32 + g * 8 + j;
                const float v = emb[d * KCODES + k];   // coalesced across k
                eT[k * DIM + d] = v;
                s = fmaf(v, v, s);                     // same chain as round-2
                const unsigned short h = f2bf(v);
                hb[j] = h;
                lb[j] = f2bf(v - bf2f(h));
            }
            uint4 H, L;
            H.x = hb[0] | ((unsigned)hb[1] << 16); H.y = hb[2] | ((unsigned)hb[3] << 16);
            H.z = hb[4] | ((unsigned)hb[5] << 16); H.w = hb[6] | ((unsigned)hb[7] << 16);
            L.x = lb[0] | ((unsigned)lb[1] << 16); L.y = lb[2] | ((unsigned)lb[3] << 16);
            L.z = lb[4] | ((unsigned)lb[5] << 16); L.w = lb[6] | ((unsigned)lb[7] << 16);
            const int lane = g * 16 + c;
            Afr[((ctg * 2 + ks) * 2 + 0) * 64 + lane] = H;   // hi
            Afr[((ctg * 2 + ks) * 2 + 1) * 64 + lane] = L;   // lo
        }
    }
    en2[k] = s;
    en2b[k] = s + 6.0f;
}

// ---------------- main: coop cvt + scan + rescan + epilogue
__global__ __launch_bounds__(THREADS, 2)
void vq_main(const float* __restrict__ x, char* __restrict__ ws,
             float* __restrict__ out) {
    __shared__ s16x8 Bfr[8][2][2][64];                // 32 KB B-fragments
    __shared__ unsigned long long sm_all[8][8][16];   // 8 KB
    __shared__ unsigned pick[ROWS_PER_BLOCK];
    __shared__ unsigned char llist[ROWS_PER_BLOCK];
    __shared__ float fbuf[DIM];
    __shared__ unsigned long long wmin[8];
    __shared__ double lpart[8];
    __shared__ int lcnt;

    const int tid = threadIdx.x;
    const int bid = blockIdx.x;
    const int w = __builtin_amdgcn_readfirstlane(tid >> 6);  // wave = 64-code group
    const int l = tid & 63;
    if (tid == 0) lcnt = 0;

    // Phase 0: cooperative x->frag conversion, once per block.
    // Thread t: row = t>>2 (coalesced 64B/thread), dims seg*16..+16.
    {
        const int r_abs = tid >> 2;          // 0..127
        const int seg   = tid & 3;
        const float* p = x + (size_t)(bid * ROWS_PER_BLOCK + r_abs) * DIM + seg * 16;
        s16x8 h0, l0, h1, l1;
        cvt8(p, h0, l0);                     // dims seg*16   .. +8
        cvt8(p + 8, h1, l1);                 // dims seg*16+8 .. +16
        const int rt = r_abs >> 4, c = r_abs & 15;
        const int jg0 = seg * 2, jg1 = seg * 2 + 1;   // 8-dim group 0..7
        Bfr[rt][jg0 >> 2][0][(jg0 & 3) * 16 + c] = h0;
        Bfr[rt][jg0 >> 2][1][(jg0 & 3) * 16 + c] = l0;
        Bfr[rt][jg1 >> 2][0][(jg1 & 3) * 16 + c] = h1;
        Bfr[rt][jg1 >> 2][1][(jg1 & 3) * 16 + c] = l1;
    }

    // A-fragments: this wave's 64 codes (4 ctiles x 2 ksteps), bf16 hi+lo.
    const s16x8* Afr = (const s16x8*)(ws + AFR_OFF);
    s16x8 Aeh[4][2], Ael[4][2];
    #pragma unroll
    for (int ct = 0; ct < 4; ++ct) {
        #pragma unroll
        for (int ks = 0; ks < 2; ++ks) {
            const int ctg = w * 4 + ct;
            Aeh[ct][ks] = Afr[((ctg * 2 + ks) * 2 + 0) * 64 + l];
            Ael[ct][ks] = Afr[((ctg * 2 + ks) * 2 + 1) * 64 + l];
        }
    }
    const float* en2b = (const float*)(ws + EN2B_OFF);
    f32x4 enf[4];
    #pragma unroll
    for (int ct = 0; ct < 4; ++ct) {
        const float4 t = *(const float4*)(en2b + w * 64 + ct * 16 + (l >> 4) * 4);
        enf[ct][0] = t.x; enf[ct][1] = t.y; enf[ct][2] = t.z; enf[ct][3] = t.w;
    }
    const int codebase = w * 64 + (l >> 4) * 4;

    __syncthreads();   // B-frags ready

    // Phase 1: scan 8 row-tiles; per ct, TWO independent 3-deep MFMA chains.
    #pragma unroll 2
    for (int bt = 0; bt < 8; ++bt) {
        const s16x8 bh0 = Bfr[bt][0][0][l];
        const s16x8 bl0 = Bfr[bt][0][1][l];
        const s16x8 bh1 = Bfr[bt][1][0][l];
        const s16x8 bl1 = Bfr[bt][1][1][l];

        unsigned m1 = 0xFFFFFFFFu, m2 = 0xFFFFFFFFu;
        #pragma unroll
        for (int ct = 0; ct < 4; ++ct) {
            f32x4 a0 = {0.f, 0.f, 0.f, 0.f};
            f32x4 a1 = {0.f, 0.f, 0.f, 0.f};
            a0 = __builtin_amdgcn_mfma_f32_16x16x32_bf16(Aeh[ct][0], bh0, a0, 0, 0, 0);
            a1 = __builtin_amdgcn_mfma_f32_16x16x32_bf16(Aeh[ct][1], bh1, a1, 0, 0, 0);
            a0 = __builtin_amdgcn_mfma_f32_16x16x32_bf16(Ael[ct][0], bh0, a0, 0, 0, 0);
            a1 = __builtin_amdgcn_mfma_f32_16x16x32_bf16(Ael[ct][1], bh1, a1, 0, 0, 0);
            a0 = __builtin_amdgcn_mfma_f32_16x16x32_bf16(Aeh[ct][0], bl0, a0, 0, 0, 0);
            a1 = __builtin_amdgcn_mfma_f32_16x16x32_bf16(Aeh[ct][1], bl1, a1, 0, 0, 0);
            #pragma unroll
            for (int rg = 0; rg < 4; ++rg) {
                const float m = fmaf(-2.0f, a0[rg] + a1[rg], enf[ct][rg]);
                const unsigned u = (__float_as_uint(m) & 0xFFFFFE00u)
                                 | (unsigned)(codebase + ct * 16 + rg);
                const unsigned hi = m1 > u ? m1 : u;
                m1 = m1 < u ? m1 : u;
                m2 = m2 < hi ? m2 : hi;
            }
        }
        #pragma unroll
        for (int mask = 16; mask <= 32; mask <<= 1) {
            const unsigned o1 = __shfl_xor(m1, mask);
            const unsigned o2 = __shfl_xor(m2, mask);
            const unsigned hi  = m1 > o1 ? m1 : o1;
            const unsigned lo2 = m2 < o2 ? m2 : o2;
            m1 = m1 < o1 ? m1 : o1;
            m2 = hi < lo2 ? hi : lo2;
        }
        if (l < 16) sm_all[bt][w][l] = ((unsigned long long)m1 << 32) | m2;
    }
    __syncthreads();

    // Phase 2: combine 8 waves per row; flag near-ties (block-local list).
    if (tid < ROWS_PER_BLOCK) {
        const int bt = tid >> 4, c = tid & 15;
        unsigned long long p = sm_all[bt][0][c];
        unsigned m1 = (unsigned)(p >> 32), m2 = (unsigned)p;
        #pragma unroll
        for (int w2 = 1; w2 < 8; ++w2) {
            p = sm_all[bt][w2][c];
            const unsigned a1 = (unsigned)(p >> 32), a2 = (unsigned)p;
            const unsigned hi  = m1 > a1 ? m1 : a1;
            const unsigned lo2 = m2 < a2 ? m2 : a2;
            m1 = m1 < a1 ? m1 : a1;
            m2 = hi < lo2 ? hi : lo2;
        }
        pick[tid] = m1 & 0x1FFu;
        const float f1 = __uint_as_float(m1 & 0xFFFFFE00u);
        const float f2 = __uint_as_float(m2 & 0xFFFFFE00u);
        if (f2 - f1 < TAU) {
            const int i = atomicAdd(&lcnt, 1);
            llist[i] = (unsigned char)tid;
        }
    }
    __syncthreads();

    // Phase 3: exact f32 rescan of flagged rows, block-parallel (1 code/thread,
    // round-2-identical per-code chain; u64 min == np.argmin tie-break).
    {
        const float* eT  = (const float*)(ws + ET_OFF);
        const float* en2 = (const float*)(ws + EN2_OFF);
        const int nfb = lcnt;
        for (int i = 0; i < nfb; ++i) {
            const int r = llist[i];
            const int grow = bid * ROWS_PER_BLOCK + r;
            if (tid < 64) fbuf[tid] = x[(size_t)grow * DIM + tid];
            __syncthreads();

            const float4* fr = (const float4*)fbuf;
            float4 a4 = make_float4(0.f, 0.f, 0.f, 0.f);
            #pragma unroll
            for (int j = 0; j < 16; ++j) {
                const float4 f = fr[j];
                a4.x = fmaf(f.x, f.x, a4.x);
                a4.y = fmaf(f.y, f.y, a4.y);
                a4.z = fmaf(f.z, f.z, a4.z);
                a4.w = fmaf(f.w, f.w, a4.w);
            }
            const float r2 = (a4.x + a4.y) + (a4.z + a4.w);

            const int k = tid;   // one code per thread
            const float4* ek = (const float4*)(eT + k * DIM);
            float4 acc4 = make_float4(0.f, 0.f, 0.f, 0.f);
            #pragma unroll
            for (int j = 0; j < 16; ++j) {
                const float4 e = ek[j];
                const float4 f = fr[j];
                acc4.x = fmaf(f.x, e.x, acc4.x);
                acc4.y = fmaf(f.y, e.y, acc4.y);
                acc4.z = fmaf(f.z, e.z, acc4.z);
                acc4.w = fmaf(f.w, e.w, acc4.w);
            }
            const float dot = (acc4.x + acc4.y) + (acc4.z + acc4.w);
            const float s = (r2 + en2[k]) - 2.0f * dot;
            unsigned long long best =
                ((unsigned long long)__float_as_uint(s) << 32) | (unsigned)k;
            #pragma unroll
            for (int mask = 1; mask <= 32; mask <<= 1) {
                const unsigned long long o = __shfl_xor(best, mask);
                if (o < best) best = o;
            }
            if (l == 0) wmin[w] = best;
            __syncthreads();
            if (tid == 0) {
                unsigned long long b = wmin[0];
                #pragma unroll
                for (int t = 1; t < 8; ++t) if (wmin[t] < b) b = wmin[t];
                pick[r] = (unsigned)(b & 0x1FFu);
            }
            __syncthreads();
        }
    }
    __syncthreads();

    // Phase 4: out = x + (q - x) and loss (4 threads per row, x re-read L2-hot)
    {
        const float* eT = (const float*)(ws + ET_OFF);
        const int r = tid >> 2, c4 = tid & 3;
        const int grow = bid * ROWS_PER_BLOCK + r;
        const float4* xr = (const float4*)(x + (size_t)grow * DIM) + c4 * 4;
        const float4* qr = (const float4*)(eT + pick[r] * DIM) + c4 * 4;
        float4* orow = ((float4*)out) + (size_t)grow * 16 + c4 * 4;
        float lsum = 0.0f;
        #pragma unroll
        for (int j = 0; j < 4; ++j) {
            const float4 q = qr[j], xv = xr[j];
            float4 o; float dx;
            dx = q.x - xv.x; o.x = xv.x + dx; lsum = fmaf(dx, dx, lsum);
            dx = q.y - xv.y; o.y = xv.y + dx; lsum = fmaf(dx, dx, lsum);
            dx = q.z - xv.z; o.z = xv.z + dx; lsum = fmaf(dx, dx, lsum);
            dx = q.w - xv.w; o.w = xv.w + dx; lsum = fmaf(dx, dx, lsum);
            orow[j] = o;
        }
        double dl = (double)lsum;
        #pragma unroll
        for (int off = 32; off > 0; off >>= 1) dl += __shfl_down(dl, off);
        if (l == 0) lpart[w] = dl;
    }
    __syncthreads();
    if (tid == 0) {
        double s = lpart[0];
        #pragma unroll
        for (int t = 1; t < 8; ++t) s += lpart[t];
        ((double*)(ws + LSLOT_OFF))[bid] = s;   // plain store, no atomic
    }
}

// ---------------- fin: deterministic loss reduce over 512 slots
__global__ __launch_bounds__(512)
void vq_fin(const double* __restrict__ slots, float* __restrict__ out) {
    __shared__ double sp[8];
    const int tid = threadIdx.x;
    double s = slots[tid];
    #pragma unroll
    for (int off = 32; off > 0; off >>= 1) s += __shfl_down(s, off);
    if ((tid & 63) == 0) sp[tid >> 6] = s;
    __syncthreads();
    if (tid == 0) {
        double t = sp[0];
        #pragma unroll
        for (int i = 1; i < 8; ++i) t += sp[i];
        out[N_ROWS * DIM] = (float)(1.25 * t * (1.0 / (double)(N_ROWS * DIM)));
    }
}

extern "C" void kernel_launch(void* const* d_in, const int* in_sizes, int n_in,
                              void* d_out, int out_size, void* d_ws, size_t ws_size,
                              hipStream_t stream) {
    const float* x   = (const float*)d_in[0];
    const float* emb = (const float*)d_in[1];
    float* out = (float*)d_out;
    char*  ws  = (char*)d_ws;

    vq_prep<<<2, 256, 0, stream>>>(emb, ws);
    vq_main<<<N_ROWS / ROWS_PER_BLOCK, THREADS, 0, stream>>>(x, ws, out);
    vq_fin<<<1, 512, 0, stream>>>((const double*)(ws + LSLOT_OFF), out);
}

// Round 18
// 58.612 us; speedup vs baseline: 1.0188x; 1.0059x over previous
//
#include <hip/hip_runtime.h>

// VectorQuantizer forward — EXACT round-14 structure; sole change: per-block
// f64 loss slots + deterministic fin reduce (no same-address atomics).
//   prep: codebook -> ws (eT f32, en2, en2b, bf16 hi+lo A-frags)  [2 blocks]
//   main (128 rows/block, 512 blocks):
//     Phase0 cooperative x->bf16 cvt into LDS frag layout (once/block)
//     Phase1 3-term bf16 MFMA scan (round-14 chain order, untouched)
//     Phase2 combine + near-tie flag
//     Phase3 exact rescan of flagged rows (round-2-identical chain)
//     Phase4 epilogue out = x + (q-x); per-block loss slot store
//   fin:  deterministic 512-slot loss reduce + scalar write
//
// Metric: argmin_k ||f-e_k||^2 == argmin_k (en2[k]-2 f.e_k). Approx dot =
// fh.eh + fh.el + fl.eh (bf16 splits), residual fl.el sigma ~4e-6;
// TAU=1.2e-3 (validated rounds 5/12/13/14, absmax 0). en2b = en2+6 keeps the
// metric positive -> u32 bit-monotone pack, code idx in low 9 bits ==
// np.argmin first-index tie-break. cvt grouping identical to rounds 13/14.

#define N_ROWS 65536
#define DIM 64
#define KCODES 512
#define ROWS_PER_BLOCK 128
#define THREADS 512

typedef short s16x8 __attribute__((ext_vector_type(8)));
typedef float f32x4 __attribute__((ext_vector_type(4)));

// ws byte offsets
#define LSLOT_OFF  0         // 512 x f64 per-block loss slots: 4 KB
#define EN2_OFF    8192
#define EN2B_OFF   10240
#define ET_OFF     12288     // f32 codebook rows: 128 KB
#define AFR_OFF    143360    // bf16 hi+lo A-frags: 128 KB

#define TAU 1.2e-3f

__device__ __forceinline__ unsigned short f2bf(float f) {
    unsigned u = __float_as_uint(f);
    return (unsigned short)((u + 0x7fffu + ((u >> 16) & 1u)) >> 16);
}
__device__ __forceinline__ float bf2f(unsigned short h) {
    return __uint_as_float(((unsigned)h) << 16);
}
__device__ __forceinline__ void cvt8(const float* __restrict__ p,
                                     s16x8& hi, s16x8& lo) {
    const float4 v0 = *(const float4*)p;
    const float4 v1 = *(const float4*)(p + 4);
    const float vv[8] = {v0.x, v0.y, v0.z, v0.w, v1.x, v1.y, v1.z, v1.w};
    #pragma unroll
    for (int j = 0; j < 8; ++j) {
        const unsigned short h = f2bf(vv[j]);
        hi[j] = (short)h;
        lo[j] = (short)f2bf(vv[j] - bf2f(h));
    }
}

// ---------------- prep: codebook only (2 blocks x 256 threads)
__global__ void vq_prep(const float* __restrict__ emb, char* __restrict__ ws) {
    const int k = blockIdx.x * 256 + threadIdx.x;   // code 0..511
    float* en2  = (float*)(ws + EN2_OFF);
    float* en2b = (float*)(ws + EN2B_OFF);
    float* eT   = (float*)(ws + ET_OFF);
    uint4* Afr  = (uint4*)(ws + AFR_OFF);
    const int ctg = k >> 4, c = k & 15;
    float s = 0.0f;
    #pragma unroll
    for (int ks = 0; ks < 2; ++ks) {
        #pragma unroll
        for (int g = 0; g < 4; ++g) {
            unsigned short hb[8], lb[8];
            #pragma unroll
            for (int j = 0; j < 8; ++j) {
                const int d = ks * 32 + g * 8 + j;
                const float v = emb[d * KCODES + k];   // coalesced across k
                eT[k * DIM + d] = v;
                s = fmaf(v, v, s);                     // same chain as round-2
                const unsigned short h = f2bf(v);
                hb[j] = h;
                lb[j] = f2bf(v - bf2f(h));
            }
            uint4 H, L;
            H.x = hb[0] | ((unsigned)hb[1] << 16); H.y = hb[2] | ((unsigned)hb[3] << 16);
            H.z = hb[4] | ((unsigned)hb[5] << 16); H.w = hb[6] | ((unsigned)hb[7] << 16);
            L.x = lb[0] | ((unsigned)lb[1] << 16); L.y = lb[2] | ((unsigned)lb[3] << 16);
            L.z = lb[4] | ((unsigned)lb[5] << 16); L.w = lb[6] | ((unsigned)lb[7] << 16);
            const int lane = g * 16 + c;
            Afr[((ctg * 2 + ks) * 2 + 0) * 64 + lane] = H;   // hi
            Afr[((ctg * 2 + ks) * 2 + 1) * 64 + lane] = L;   // lo
        }
    }
    en2[k] = s;
    en2b[k] = s + 6.0f;
}

// ---------------- main: coop cvt + scan + rescan + epilogue
__global__ __launch_bounds__(THREADS, 2)
void vq_main(const float* __restrict__ x, char* __restrict__ ws,
             float* __restrict__ out) {
    __shared__ s16x8 Bfr[8][2][2][64];                // 32 KB B-fragments
    __shared__ unsigned long long sm_all[8][8][16];   // 8 KB
    __shared__ unsigned pick[ROWS_PER_BLOCK];
    __shared__ unsigned char llist[ROWS_PER_BLOCK];
    __shared__ float fbuf[DIM];
    __shared__ unsigned long long wmin[8];
    __shared__ double lpart[8];
    __shared__ int lcnt;

    const int tid = threadIdx.x;
    const int bid = blockIdx.x;
    const int w = __builtin_amdgcn_readfirstlane(tid >> 6);  // wave = 64-code group
    const int l = tid & 63;
    if (tid == 0) lcnt = 0;

    // Phase 0: cooperative x->frag conversion, once per block.
    // Thread t: row = t>>2 (coalesced 64B/thread), dims seg*16..+16.
    {
        const int r_abs = tid >> 2;          // 0..127
        const int seg   = tid & 3;
        const float* p = x + (size_t)(bid * ROWS_PER_BLOCK + r_abs) * DIM + seg * 16;
        s16x8 h0, l0, h1, l1;
        cvt8(p, h0, l0);                     // dims seg*16   .. +8
        cvt8(p + 8, h1, l1);                 // dims seg*16+8 .. +16
        const int rt = r_abs >> 4, c = r_abs & 15;
        const int jg0 = seg * 2, jg1 = seg * 2 + 1;   // 8-dim group 0..7
        Bfr[rt][jg0 >> 2][0][(jg0 & 3) * 16 + c] = h0;
        Bfr[rt][jg0 >> 2][1][(jg0 & 3) * 16 + c] = l0;
        Bfr[rt][jg1 >> 2][0][(jg1 & 3) * 16 + c] = h1;
        Bfr[rt][jg1 >> 2][1][(jg1 & 3) * 16 + c] = l1;
    }

    // A-fragments: this wave's 64 codes (4 ctiles x 2 ksteps), bf16 hi+lo.
    const s16x8* Afr = (const s16x8*)(ws + AFR_OFF);
    s16x8 Aeh[4][2], Ael[4][2];
    #pragma unroll
    for (int ct = 0; ct < 4; ++ct) {
        #pragma unroll
        for (int ks = 0; ks < 2; ++ks) {
            const int ctg = w * 4 + ct;
            Aeh[ct][ks] = Afr[((ctg * 2 + ks) * 2 + 0) * 64 + l];
            Ael[ct][ks] = Afr[((ctg * 2 + ks) * 2 + 1) * 64 + l];
        }
    }
    const float* en2b = (const float*)(ws + EN2B_OFF);
    f32x4 enf[4];
    #pragma unroll
    for (int ct = 0; ct < 4; ++ct) {
        const float4 t = *(const float4*)(en2b + w * 64 + ct * 16 + (l >> 4) * 4);
        enf[ct][0] = t.x; enf[ct][1] = t.y; enf[ct][2] = t.z; enf[ct][3] = t.w;
    }
    const int codebase = w * 64 + (l >> 4) * 4;

    __syncthreads();   // B-frags ready

    // Phase 1: scan 8 row-tiles; B-frags from LDS (round-14 chain order).
    #pragma unroll 2
    for (int bt = 0; bt < 8; ++bt) {
        const s16x8 bh0 = Bfr[bt][0][0][l];
        const s16x8 bl0 = Bfr[bt][0][1][l];
        const s16x8 bh1 = Bfr[bt][1][0][l];
        const s16x8 bl1 = Bfr[bt][1][1][l];

        unsigned m1 = 0xFFFFFFFFu, m2 = 0xFFFFFFFFu;
        #pragma unroll
        for (int ct = 0; ct < 4; ++ct) {
            f32x4 a = {0.f, 0.f, 0.f, 0.f};
            a = __builtin_amdgcn_mfma_f32_16x16x32_bf16(Aeh[ct][0], bh0, a, 0, 0, 0);
            a = __builtin_amdgcn_mfma_f32_16x16x32_bf16(Aeh[ct][1], bh1, a, 0, 0, 0);
            a = __builtin_amdgcn_mfma_f32_16x16x32_bf16(Ael[ct][0], bh0, a, 0, 0, 0);
            a = __builtin_amdgcn_mfma_f32_16x16x32_bf16(Ael[ct][1], bh1, a, 0, 0, 0);
            a = __builtin_amdgcn_mfma_f32_16x16x32_bf16(Aeh[ct][0], bl0, a, 0, 0, 0);
            a = __builtin_amdgcn_mfma_f32_16x16x32_bf16(Aeh[ct][1], bl1, a, 0, 0, 0);
            #pragma unroll
            for (int rg = 0; rg < 4; ++rg) {
                const float m = fmaf(-2.0f, a[rg], enf[ct][rg]);
                const unsigned u = (__float_as_uint(m) & 0xFFFFFE00u)
                                 | (unsigned)(codebase + ct * 16 + rg);
                const unsigned hi = m1 > u ? m1 : u;
                m1 = m1 < u ? m1 : u;
                m2 = m2 < hi ? m2 : hi;
            }
        }
        #pragma unroll
        for (int mask = 16; mask <= 32; mask <<= 1) {
            const unsigned o1 = __shfl_xor(m1, mask);
            const unsigned o2 = __shfl_xor(m2, mask);
            const unsigned hi  = m1 > o1 ? m1 : o1;
            const unsigned lo2 = m2 < o2 ? m2 : o2;
            m1 = m1 < o1 ? m1 : o1;
            m2 = hi < lo2 ? hi : lo2;
        }
        if (l < 16) sm_all[bt][w][l] = ((unsigned long long)m1 << 32) | m2;
    }
    __syncthreads();

    // Phase 2: combine 8 waves per row; flag near-ties (block-local list).
    if (tid < ROWS_PER_BLOCK) {
        const int bt = tid >> 4, c = tid & 15;
        unsigned long long p = sm_all[bt][0][c];
        unsigned m1 = (unsigned)(p >> 32), m2 = (unsigned)p;
        #pragma unroll
        for (int w2 = 1; w2 < 8; ++w2) {
            p = sm_all[bt][w2][c];
            const unsigned a1 = (unsigned)(p >> 32), a2 = (unsigned)p;
            const unsigned hi  = m1 > a1 ? m1 : a1;
            const unsigned lo2 = m2 < a2 ? m2 : a2;
            m1 = m1 < a1 ? m1 : a1;
            m2 = hi < lo2 ? hi : lo2;
        }
        pick[tid] = m1 & 0x1FFu;
        const float f1 = __uint_as_float(m1 & 0xFFFFFE00u);
        const float f2 = __uint_as_float(m2 & 0xFFFFFE00u);
        if (f2 - f1 < TAU) {
            const int i = atomicAdd(&lcnt, 1);
            llist[i] = (unsigned char)tid;
        }
    }
    __syncthreads();

    // Phase 3: exact f32 rescan of flagged rows, block-parallel (1 code/thread,
    // round-2-identical per-code chain; u64 min == np.argmin tie-break).
    {
        const float* eT  = (const float*)(ws + ET_OFF);
        const float* en2 = (const float*)(ws + EN2_OFF);
        const int nfb = lcnt;
        for (int i = 0; i < nfb; ++i) {
            const int r = llist[i];
            const int grow = bid * ROWS_PER_BLOCK + r;
            if (tid < 64) fbuf[tid] = x[(size_t)grow * DIM + tid];
            __syncthreads();

            const float4* fr = (const float4*)fbuf;
            float4 a4 = make_float4(0.f, 0.f, 0.f, 0.f);
            #pragma unroll
            for (int j = 0; j < 16; ++j) {
                const float4 f = fr[j];
                a4.x = fmaf(f.x, f.x, a4.x);
                a4.y = fmaf(f.y, f.y, a4.y);
                a4.z = fmaf(f.z, f.z, a4.z);
                a4.w = fmaf(f.w, f.w, a4.w);
            }
            const float r2 = (a4.x + a4.y) + (a4.z + a4.w);

            const int k = tid;   // one code per thread
            const float4* ek = (const float4*)(eT + k * DIM);
            float4 acc4 = make_float4(0.f, 0.f, 0.f, 0.f);
            #pragma unroll
            for (int j = 0; j < 16; ++j) {
                const float4 e = ek[j];
                const float4 f = fr[j];
                acc4.x = fmaf(f.x, e.x, acc4.x);
                acc4.y = fmaf(f.y, e.y, acc4.y);
                acc4.z = fmaf(f.z, e.z, acc4.z);
                acc4.w = fmaf(f.w, e.w, acc4.w);
            }
            const float dot = (acc4.x + acc4.y) + (acc4.z + acc4.w);
            const float s = (r2 + en2[k]) - 2.0f * dot;
            unsigned long long best =
                ((unsigned long long)__float_as_uint(s) << 32) | (unsigned)k;
            #pragma unroll
            for (int mask = 1; mask <= 32; mask <<= 1) {
                const unsigned long long o = __shfl_xor(best, mask);
                if (o < best) best = o;
            }
            if (l == 0) wmin[w] = best;
            __syncthreads();
            if (tid == 0) {
                unsigned long long b = wmin[0];
                #pragma unroll
                for (int t = 1; t < 8; ++t) if (wmin[t] < b) b = wmin[t];
                pick[r] = (unsigned)(b & 0x1FFu);
            }
            __syncthreads();
        }
    }
    __syncthreads();

    // Phase 4: out = x + (q - x) and loss (4 threads per row, x re-read L2-hot)
    {
        const float* eT = (const float*)(ws + ET_OFF);
        const int r = tid >> 2, c4 = tid & 3;
        const int grow = bid * ROWS_PER_BLOCK + r;
        const float4* xr = (const float4*)(x + (size_t)grow * DIM) + c4 * 4;
        const float4* qr = (const float4*)(eT + pick[r] * DIM) + c4 * 4;
        float4* orow = ((float4*)out) + (size_t)grow * 16 + c4 * 4;
        float lsum = 0.0f;
        #pragma unroll
        for (int j = 0; j < 4; ++j) {
            const float4 q = qr[j], xv = xr[j];
            float4 o; float dx;
            dx = q.x - xv.x; o.x = xv.x + dx; lsum = fmaf(dx, dx, lsum);
            dx = q.y - xv.y; o.y = xv.y + dx; lsum = fmaf(dx, dx, lsum);
            dx = q.z - xv.z; o.z = xv.z + dx; lsum = fmaf(dx, dx, lsum);
            dx = q.w - xv.w; o.w = xv.w + dx; lsum = fmaf(dx, dx, lsum);
            orow[j] = o;
        }
        double dl = (double)lsum;
        #pragma unroll
        for (int off = 32; off > 0; off >>= 1) dl += __shfl_down(dl, off);
        if (l == 0) lpart[w] = dl;
    }
    __syncthreads();
    if (tid == 0) {
        double s = lpart[0];
        #pragma unroll
        for (int t = 1; t < 8; ++t) s += lpart[t];
        ((double*)(ws + LSLOT_OFF))[bid] = s;   // plain store, no atomic
    }
}

// ---------------- fin: deterministic loss reduce over 512 slots
__global__ __launch_bounds__(512)
void vq_fin(const double* __restrict__ slots, float* __restrict__ out) {
    __shared__ double sp[8];
    const int tid = threadIdx.x;
    double s = slots[tid];
    #pragma unroll
    for (int off = 32; off > 0; off >>= 1) s += __shfl_down(s, off);
    if ((tid & 63) == 0) sp[tid >> 6] = s;
    __syncthreads();
    if (tid == 0) {
        double t = sp[0];
        #pragma unroll
        for (int i = 1; i < 8; ++i) t += sp[i];
        out[N_ROWS * DIM] = (float)(1.25 * t * (1.0 / (double)(N_ROWS * DIM)));
    }
}

extern "C" void kernel_launch(void* const* d_in, const int* in_sizes, int n_in,
                              void* d_out, int out_size, void* d_ws, size_t ws_size,
                              hipStream_t stream) {
    const float* x   = (const float*)d_in[0];
    const float* emb = (const float*)d_in[1];
    float* out = (float*)d_out;
    char*  ws  = (char*)d_ws;

    vq_prep<<<2, 256, 0, stream>>>(emb, ws);
    vq_main<<<N_ROWS / ROWS_PER_BLOCK, THREADS, 0, stream>>>(x, ws, out);
    vq_fin<<<1, 512, 0, stream>>>((const double*)(ws + LSLOT_OFF), out);
}

// Round 19
// 45.619 us; speedup vs baseline: 1.3089x; 1.2848x over previous
//
#include <hip/hip_runtime.h>

// VectorQuantizer forward, fused 3-launch structure + cooperative cvt:
//   prep: codebook -> ws (eT f32, en2, en2b, bf16 hi+lo A-frags)  [2 blocks]
//   main: Phase0 cooperative x->bf16 cvt into LDS frag layout (once/block),
//         Phase1 3-term bf16 MFMA scan (B-frags via conflict-free ds_read),
//         Phase2 combine + near-tie flag, Phase3 exact rescan (round-2 chain),
//         Phase4 streaming epilogue + loss
//   fin:  loss scalar
//
// NOTE (round 19): byte-exact revert to the round-14 kernel (best measured:
// main 39.96us, total 45.8us). Rounds 16-18 showed that making ws a written-to
// pointer in vq_main costs ~12us (defeats SMEM scalarization of codebook
// loads: s_load requires provably no aliasing in-kernel VMEM store), so ws
// stays const here and loss uses the separate loss_acc pointer + atomicAdd.
//
// Metric: argmin_k ||f-e_k||^2 == argmin_k (en2[k]-2 f.e_k). Approx dot =
// fh.eh + fh.el + fl.eh (bf16 splits), residual fl.el sigma ~4e-6;
// TAU=1.2e-3 (validated rounds 5/12/13/14, absmax 0). en2b = en2+6 keeps the
// metric positive -> u32 bit-monotone pack, code idx in low 9 bits ==
// np.argmin first-index tie-break. cvt8 grouping (8-aligned dims) identical
// to round 13 -> same bf16 inputs -> same picks.

#define N_ROWS 65536
#define DIM 64
#define KCODES 512
#define ROWS_PER_BLOCK 128
#define THREADS 512

typedef short s16x8 __attribute__((ext_vector_type(8)));
typedef float f32x4 __attribute__((ext_vector_type(4)));

// ws byte offsets
#define LOSS_OFF   0
#define EN2_OFF    256
#define EN2B_OFF   2304
#define ET_OFF     4352      // f32 codebook rows: 128 KB
#define AFR_OFF    135424    // bf16 hi+lo A-frags: 128 KB

#define TAU 1.2e-3f

__device__ __forceinline__ unsigned short f2bf(float f) {
    unsigned u = __float_as_uint(f);
    return (unsigned short)((u + 0x7fffu + ((u >> 16) & 1u)) >> 16);
}
__device__ __forceinline__ float bf2f(unsigned short h) {
    return __uint_as_float(((unsigned)h) << 16);
}
__device__ __forceinline__ void cvt8(const float* __restrict__ p,
                                     s16x8& hi, s16x8& lo) {
    const float4 v0 = *(const float4*)p;
    const float4 v1 = *(const float4*)(p + 4);
    const float vv[8] = {v0.x, v0.y, v0.z, v0.w, v1.x, v1.y, v1.z, v1.w};
    #pragma unroll
    for (int j = 0; j < 8; ++j) {
        const unsigned short h = f2bf(vv[j]);
        hi[j] = (short)h;
        lo[j] = (short)f2bf(vv[j] - bf2f(h));
    }
}

// ---------------- prep: codebook only (2 blocks x 256 threads)
__global__ void vq_prep(const float* __restrict__ emb, char* __restrict__ ws) {
    const int k = blockIdx.x * 256 + threadIdx.x;   // code 0..511
    if (k == 0) *(double*)(ws + LOSS_OFF) = 0.0;
    float* en2  = (float*)(ws + EN2_OFF);
    float* en2b = (float*)(ws + EN2B_OFF);
    float* eT   = (float*)(ws + ET_OFF);
    uint4* Afr  = (uint4*)(ws + AFR_OFF);
    const int ctg = k >> 4, c = k & 15;
    float s = 0.0f;
    #pragma unroll
    for (int ks = 0; ks < 2; ++ks) {
        #pragma unroll
        for (int g = 0; g < 4; ++g) {
            unsigned short hb[8], lb[8];
            #pragma unroll
            for (int j = 0; j < 8; ++j) {
                const int d = ks * 32 + g * 8 + j;
                const float v = emb[d * KCODES + k];   // coalesced across k
                eT[k * DIM + d] = v;
                s = fmaf(v, v, s);                     // same chain as round-2
                const unsigned short h = f2bf(v);
                hb[j] = h;
                lb[j] = f2bf(v - bf2f(h));
            }
            uint4 H, L;
            H.x = hb[0] | ((unsigned)hb[1] << 16); H.y = hb[2] | ((unsigned)hb[3] << 16);
            H.z = hb[4] | ((unsigned)hb[5] << 16); H.w = hb[6] | ((unsigned)hb[7] << 16);
            L.x = lb[0] | ((unsigned)lb[1] << 16); L.y = lb[2] | ((unsigned)lb[3] << 16);
            L.z = lb[4] | ((unsigned)lb[5] << 16); L.w = lb[6] | ((unsigned)lb[7] << 16);
            const int lane = g * 16 + c;
            Afr[((ctg * 2 + ks) * 2 + 0) * 64 + lane] = H;   // hi
            Afr[((ctg * 2 + ks) * 2 + 1) * 64 + lane] = L;   // lo
        }
    }
    en2[k] = s;
    en2b[k] = s + 6.0f;
}

// ---------------- main: coop cvt + scan + rescan + epilogue
__global__ __launch_bounds__(THREADS, 2)
void vq_main(const float* __restrict__ x, const char* __restrict__ ws,
             float* __restrict__ out, double* __restrict__ loss_acc) {
    __shared__ s16x8 Bfr[8][2][2][64];                // 32 KB B-fragments
    __shared__ unsigned long long sm_all[8][8][16];   // 8 KB
    __shared__ unsigned pick[ROWS_PER_BLOCK];
    __shared__ unsigned char llist[ROWS_PER_BLOCK];
    __shared__ float fbuf[DIM];
    __shared__ unsigned long long wmin[8];
    __shared__ double lpart[8];
    __shared__ int lcnt;

    const int tid = threadIdx.x;
    const int bid = blockIdx.x;
    const int w = __builtin_amdgcn_readfirstlane(tid >> 6);  // wave = 64-code group
    const int l = tid & 63;
    if (tid == 0) lcnt = 0;

    // Phase 0: cooperative x->frag conversion, once per block.
    // Thread t: row = t>>2 (coalesced 64B/thread), dims seg*16..+16.
    {
        const int r_abs = tid >> 2;          // 0..127
        const int seg   = tid & 3;
        const float* p = x + (size_t)(bid * ROWS_PER_BLOCK + r_abs) * DIM + seg * 16;
        s16x8 h0, l0, h1, l1;
        cvt8(p, h0, l0);                     // dims seg*16   .. +8
        cvt8(p + 8, h1, l1);                 // dims seg*16+8 .. +16
        const int rt = r_abs >> 4, c = r_abs & 15;
        const int jg0 = seg * 2, jg1 = seg * 2 + 1;   // 8-dim group 0..7
        Bfr[rt][jg0 >> 2][0][(jg0 & 3) * 16 + c] = h0;
        Bfr[rt][jg0 >> 2][1][(jg0 & 3) * 16 + c] = l0;
        Bfr[rt][jg1 >> 2][0][(jg1 & 3) * 16 + c] = h1;
        Bfr[rt][jg1 >> 2][1][(jg1 & 3) * 16 + c] = l1;
    }

    // A-fragments: this wave's 64 codes (4 ctiles x 2 ksteps), bf16 hi+lo.
    const s16x8* Afr = (const s16x8*)(ws + AFR_OFF);
    s16x8 Aeh[4][2], Ael[4][2];
    #pragma unroll
    for (int ct = 0; ct < 4; ++ct) {
        #pragma unroll
        for (int ks = 0; ks < 2; ++ks) {
            const int ctg = w * 4 + ct;
            Aeh[ct][ks] = Afr[((ctg * 2 + ks) * 2 + 0) * 64 + l];
            Ael[ct][ks] = Afr[((ctg * 2 + ks) * 2 + 1) * 64 + l];
        }
    }
    const float* en2b = (const float*)(ws + EN2B_OFF);
    f32x4 enf[4];
    #pragma unroll
    for (int ct = 0; ct < 4; ++ct) {
        const float4 t = *(const float4*)(en2b + w * 64 + ct * 16 + (l >> 4) * 4);
        enf[ct][0] = t.x; enf[ct][1] = t.y; enf[ct][2] = t.z; enf[ct][3] = t.w;
    }
    const int codebase = w * 64 + (l >> 4) * 4;

    __syncthreads();   // B-frags ready

    // Phase 1: scan 8 row-tiles; B-frags from LDS (conflict-free ds_read_b128).
    #pragma unroll 2
    for (int bt = 0; bt < 8; ++bt) {
        const s16x8 bh0 = Bfr[bt][0][0][l];
        const s16x8 bl0 = Bfr[bt][0][1][l];
        const s16x8 bh1 = Bfr[bt][1][0][l];
        const s16x8 bl1 = Bfr[bt][1][1][l];

        unsigned m1 = 0xFFFFFFFFu, m2 = 0xFFFFFFFFu;
        #pragma unroll
        for (int ct = 0; ct < 4; ++ct) {
            f32x4 a = {0.f, 0.f, 0.f, 0.f};
            a = __builtin_amdgcn_mfma_f32_16x16x32_bf16(Aeh[ct][0], bh0, a, 0, 0, 0);
            a = __builtin_amdgcn_mfma_f32_16x16x32_bf16(Aeh[ct][1], bh1, a, 0, 0, 0);
            a = __builtin_amdgcn_mfma_f32_16x16x32_bf16(Ael[ct][0], bh0, a, 0, 0, 0);
            a = __builtin_amdgcn_mfma_f32_16x16x32_bf16(Ael[ct][1], bh1, a, 0, 0, 0);
            a = __builtin_amdgcn_mfma_f32_16x16x32_bf16(Aeh[ct][0], bl0, a, 0, 0, 0);
            a = __builtin_amdgcn_mfma_f32_16x16x32_bf16(Aeh[ct][1], bl1, a, 0, 0, 0);
            #pragma unroll
            for (int rg = 0; rg < 4; ++rg) {
                const float m = fmaf(-2.0f, a[rg], enf[ct][rg]);
                const unsigned u = (__float_as_uint(m) & 0xFFFFFE00u)
                                 | (unsigned)(codebase + ct * 16 + rg);
                const unsigned hi = m1 > u ? m1 : u;
                m1 = m1 < u ? m1 : u;
                m2 = m2 < hi ? m2 : hi;
            }
        }
        #pragma unroll
        for (int mask = 16; mask <= 32; mask <<= 1) {
            const unsigned o1 = __shfl_xor(m1, mask);
            const unsigned o2 = __shfl_xor(m2, mask);
            const unsigned hi  = m1 > o1 ? m1 : o1;
            const unsigned lo2 = m2 < o2 ? m2 : o2;
            m1 = m1 < o1 ? m1 : o1;
            m2 = hi < lo2 ? hi : lo2;
        }
        if (l < 16) sm_all[bt][w][l] = ((unsigned long long)m1 << 32) | m2;
    }
    __syncthreads();

    // Phase 2: combine 8 waves per row; flag near-ties (block-local list).
    if (tid < ROWS_PER_BLOCK) {
        const int bt = tid >> 4, c = tid & 15;
        unsigned long long p = sm_all[bt][0][c];
        unsigned m1 = (unsigned)(p >> 32), m2 = (unsigned)p;
        #pragma unroll
        for (int w2 = 1; w2 < 8; ++w2) {
            p = sm_all[bt][w2][c];
            const unsigned a1 = (unsigned)(p >> 32), a2 = (unsigned)p;
            const unsigned hi  = m1 > a1 ? m1 : a1;
            const unsigned lo2 = m2 < a2 ? m2 : a2;
            m1 = m1 < a1 ? m1 : a1;
            m2 = hi < lo2 ? hi : lo2;
        }
        pick[tid] = m1 & 0x1FFu;
        const float f1 = __uint_as_float(m1 & 0xFFFFFE00u);
        const float f2 = __uint_as_float(m2 & 0xFFFFFE00u);
        if (f2 - f1 < TAU) {
            const int i = atomicAdd(&lcnt, 1);
            llist[i] = (unsigned char)tid;
        }
    }
    __syncthreads();

    // Phase 3: exact f32 rescan of flagged rows, block-parallel (1 code/thread,
    // round-2-identical per-code chain; u64 min == np.argmin tie-break).
    {
        const float* eT  = (const float*)(ws + ET_OFF);
        const float* en2 = (const float*)(ws + EN2_OFF);
        const int nfb = lcnt;
        for (int i = 0; i < nfb; ++i) {
            const int r = llist[i];
            const int grow = bid * ROWS_PER_BLOCK + r;
            if (tid < 64) fbuf[tid] = x[(size_t)grow * DIM + tid];
            __syncthreads();

            const float4* fr = (const float4*)fbuf;
            float4 a4 = make_float4(0.f, 0.f, 0.f, 0.f);
            #pragma unroll
            for (int j = 0; j < 16; ++j) {
                const float4 f = fr[j];
                a4.x = fmaf(f.x, f.x, a4.x);
                a4.y = fmaf(f.y, f.y, a4.y);
                a4.z = fmaf(f.z, f.z, a4.z);
                a4.w = fmaf(f.w, f.w, a4.w);
            }
            const float r2 = (a4.x + a4.y) + (a4.z + a4.w);

            const int k = tid;   // one code per thread
            const float4* ek = (const float4*)(eT + k * DIM);
            float4 acc4 = make_float4(0.f, 0.f, 0.f, 0.f);
            #pragma unroll
            for (int j = 0; j < 16; ++j) {
                const float4 e = ek[j];
                const float4 f = fr[j];
                acc4.x = fmaf(f.x, e.x, acc4.x);
                acc4.y = fmaf(f.y, e.y, acc4.y);
                acc4.z = fmaf(f.z, e.z, acc4.z);
                acc4.w = fmaf(f.w, e.w, acc4.w);
            }
            const float dot = (acc4.x + acc4.y) + (acc4.z + acc4.w);
            const float s = (r2 + en2[k]) - 2.0f * dot;
            unsigned long long best =
                ((unsigned long long)__float_as_uint(s) << 32) | (unsigned)k;
            #pragma unroll
            for (int mask = 1; mask <= 32; mask <<= 1) {
                const unsigned long long o = __shfl_xor(best, mask);
                if (o < best) best = o;
            }
            if (l == 0) wmin[w] = best;
            __syncthreads();
            if (tid == 0) {
                unsigned long long b = wmin[0];
                #pragma unroll
                for (int t = 1; t < 8; ++t) if (wmin[t] < b) b = wmin[t];
                pick[r] = (unsigned)(b & 0x1FFu);
            }
            __syncthreads();
        }
    }
    __syncthreads();

    // Phase 4: out = x + (q - x) and loss (4 threads per row, x re-read L2-hot)
    {
        const float* eT = (const float*)(ws + ET_OFF);
        const int r = tid >> 2, c4 = tid & 3;
        const int grow = bid * ROWS_PER_BLOCK + r;
        const float4* xr = (const float4*)(x + (size_t)grow * DIM) + c4 * 4;
        const float4* qr = (const float4*)(eT + pick[r] * DIM) + c4 * 4;
        float4* orow = ((float4*)out) + (size_t)grow * 16 + c4 * 4;
        float lsum = 0.0f;
        #pragma unroll
        for (int j = 0; j < 4; ++j) {
            const float4 q = qr[j], xv = xr[j];
            float4 o; float dx;
            dx = q.x - xv.x; o.x = xv.x + dx; lsum = fmaf(dx, dx, lsum);
            dx = q.y - xv.y; o.y = xv.y + dx; lsum = fmaf(dx, dx, lsum);
            dx = q.z - xv.z; o.z = xv.z + dx; lsum = fmaf(dx, dx, lsum);
            dx = q.w - xv.w; o.w = xv.w + dx; lsum = fmaf(dx, dx, lsum);
            orow[j] = o;
        }
        double dl = (double)lsum;
        #pragma unroll
        for (int off = 32; off > 0; off >>= 1) dl += __shfl_down(dl, off);
        if (l == 0) lpart[w] = dl;
    }
    __syncthreads();
    if (tid == 0) {
        double s = lpart[0];
        #pragma unroll
        for (int t = 1; t < 8; ++t) s += lpart[t];
        atomicAdd(loss_acc, s);
    }
}

__global__ void vq_fin(const double* __restrict__ loss_acc, float* __restrict__ out) {
    if (threadIdx.x == 0)
        out[N_ROWS * DIM] = (float)(1.25 * loss_acc[0] * (1.0 / (double)(N_ROWS * DIM)));
}

extern "C" void kernel_launch(void* const* d_in, const int* in_sizes, int n_in,
                              void* d_out, int out_size, void* d_ws, size_t ws_size,
                              hipStream_t stream) {
    const float* x   = (const float*)d_in[0];
    const float* emb = (const float*)d_in[1];
    float* out = (float*)d_out;
    char*  ws  = (char*)d_ws;

    vq_prep<<<2, 256, 0, stream>>>(emb, ws);
    vq_main<<<N_ROWS / ROWS_PER_BLOCK, THREADS, 0, stream>>>(
        x, ws, out, (double*)(ws + LOSS_OFF));
    vq_fin<<<1, 1, 0, stream>>>((const double*)(ws + LOSS_OFF), out);
}